// Round 3
// baseline (1469.912 us; speedup 1.0000x reference)
//
#include <hip/hip_runtime.h>

// GCN 2-layer: 256 -> 16 -> 1, N=100000, E=3.2M + self loops.
// R3: bucket-binned aggregation (G=128 nodes/bucket), LDS-tile accumulate.
//   out[d] = isq[d]*(sum_src ts[src] + ts[d]) + b2,  ts = (h2 @ W2)*isq
//   h2 = relu(isq[d]*(sum_src hs[src] + hs[d]) + b1), hs = (x @ W1)*isq
// Edge pack: (src<<7)|(dst&127); bucket = dst>>7. src<2^17 so fits 24 bits.

#define G 128               // nodes per bucket
#define GSH 7
#define BMAX 1024           // scan width (B=782 for N=100000)

__global__ void k_deg(const int* __restrict__ dst, int E, int* __restrict__ deg) {
    int e = blockIdx.x * blockDim.x + threadIdx.x;
    if (e < E) atomicAdd(&deg[dst[e]], 1);
}

__global__ void k_isq(const int* __restrict__ deg, float* __restrict__ isq, int N) {
    int n = blockIdx.x * blockDim.x + threadIdx.x;
    if (n < N) isq[n] = rsqrtf((float)(deg[n] + 1));   // +1 self loop
}

// bucket counts = sum of deg over the bucket's node range
__global__ void k_bcnt(const int* __restrict__ deg, int N, int* __restrict__ bcnt) {
    __shared__ int s[G];
    int t = threadIdx.x, i = (blockIdx.x << GSH) + t;
    s[t] = (i < N) ? deg[i] : 0;
    __syncthreads();
    for (int off = G / 2; off > 0; off >>= 1) {
        if (t < off) s[t] += s[t + off];
        __syncthreads();
    }
    if (t == 0) bcnt[blockIdx.x] = s[0];
}

// exclusive scan of 16-padded bucket counts -> boff (single block)
__global__ void k_scanB(const int* __restrict__ bcnt, int B, int* __restrict__ boff) {
    __shared__ int s[BMAX];
    int t = threadIdx.x;
    int v = (t < B) ? ((bcnt[t] + 15) & ~15) : 0;
    s[t] = v;
    __syncthreads();
    for (int off = 1; off < BMAX; off <<= 1) {
        int x = (t >= off) ? s[t - off] : 0;
        __syncthreads();
        s[t] += x;
        __syncthreads();
    }
    if (t < B) boff[t] = s[t] - v;
}

// bin edges into bucket regions; packed int per edge. Active write set ~B
// cache lines (consecutive cursor claims are temporally adjacent) -> ~13MB.
__global__ void k_bin(const int* __restrict__ src, const int* __restrict__ dst,
                      const int* __restrict__ boff, int* __restrict__ cursor,
                      int* __restrict__ pairs, int E) {
    int e = blockIdx.x * blockDim.x + threadIdx.x;
    if (e < E) {
        int d = dst[e];
        int b = d >> GSH;
        int pos = boff[b] + atomicAdd(&cursor[b], 1);
        pairs[pos] = (src[e] << GSH) | (d & (G - 1));
    }
}

// hs[n][f] = dot(x[n,:], W1[:,f]) * isq[n].  2 nodes x 2 features / thread.
// Tile = 32 nodes; block = 128 threads (16 node-pairs x 8 feature-pairs).
__global__ __launch_bounds__(128) void k_lin1(
    const float* __restrict__ x, const float* __restrict__ W1,
    const float* __restrict__ isq, float* __restrict__ hs, int N, int ntiles)
{
    __shared__ float xs[32][260];
    __shared__ float wT[16][260];
    const int t = threadIdx.x;
    #pragma unroll
    for (int i = 0; i < 32; ++i) {
        int idx = t + i * 128;               // 4096 elems of W1[256][16]
        wT[idx & 15][idx >> 4] = W1[idx];
    }
    const int np = t >> 3, fp = t & 7;       // node-pair, feature-pair
    for (int tile = blockIdx.x; tile < ntiles; tile += gridDim.x) {
        const int n0 = tile << 5;
        __syncthreads();                     // xs reuse + wT ready
        #pragma unroll
        for (int i = 0; i < 16; ++i) {
            int fi = t + i * 128;            // float4 index 0..2047
            int r = fi >> 6, c4 = fi & 63;
            int n = n0 + r;
            float4 v = (n < N) ? ((const float4*)(x + ((size_t)n << 8)))[c4]
                               : make_float4(0.f, 0.f, 0.f, 0.f);
            *(float4*)&xs[r][c4 * 4] = v;
        }
        __syncthreads();
        const float4* xr0 = (const float4*)&xs[2 * np][0];
        const float4* xr1 = (const float4*)&xs[2 * np + 1][0];
        const float4* wr0 = (const float4*)&wT[2 * fp][0];
        const float4* wr1 = (const float4*)&wT[2 * fp + 1][0];
        float a00 = 0.f, a01 = 0.f, a10 = 0.f, a11 = 0.f;
        #pragma unroll 8
        for (int k4 = 0; k4 < 64; ++k4) {
            float4 xa = xr0[k4], xb = xr1[k4];
            float4 wa = wr0[k4], wb = wr1[k4];
            a00 += xa.x * wa.x + xa.y * wa.y + xa.z * wa.z + xa.w * wa.w;
            a01 += xa.x * wb.x + xa.y * wb.y + xa.z * wb.z + xa.w * wb.w;
            a10 += xb.x * wa.x + xb.y * wa.y + xb.z * wa.z + xb.w * wa.w;
            a11 += xb.x * wb.x + xb.y * wb.y + xb.z * wb.z + xb.w * wb.w;
        }
        int na = n0 + 2 * np, nb = na + 1;
        int f0 = 2 * fp, f1 = f0 + 1;
        if (na < N) {
            float iq = isq[na];
            hs[na * 16 + f0] = a00 * iq;
            hs[na * 16 + f1] = a01 * iq;
        }
        if (nb < N) {
            float iq = isq[nb];
            hs[nb * 16 + f0] = a10 * iq;
            hs[nb * 16 + f1] = a11 * iq;
        }
    }
}

// Layer-1 aggregation into LDS tile + fused relu/W2/isq epilogue -> ts.
__global__ __launch_bounds__(256) void k_agg1(
    const int* __restrict__ pairs, const int* __restrict__ boff,
    const int* __restrict__ bcnt, const float* __restrict__ hs,
    const float* __restrict__ isq, const float* __restrict__ b1,
    const float* __restrict__ W2, float* __restrict__ ts, int N)
{
    __shared__ float agg[G * 16];            // 8KB
    const int t = threadIdx.x, k = blockIdx.x;
    const int slot = t >> 4, f = t & 15;
    const float bf = b1[f], wf = W2[f];
    #pragma unroll
    for (int i = t; i < G * 16; i += 256) agg[i] = 0.f;
    const int beg = boff[k], cnt = bcnt[k];
    __syncthreads();
    const int4* p4 = (const int4*)(pairs + beg);   // beg is 16-int aligned
    const int nq = (cnt + 3) >> 2;
    for (int q = slot; q < nq; q += 16) {
        int4 pk = p4[q];
        int base = q << 2;
        if (base < cnt)     atomicAdd(&agg[(pk.x & (G-1)) * 16 + f], hs[(pk.x >> GSH) * 16 + f]);
        if (base + 1 < cnt) atomicAdd(&agg[(pk.y & (G-1)) * 16 + f], hs[(pk.y >> GSH) * 16 + f]);
        if (base + 2 < cnt) atomicAdd(&agg[(pk.z & (G-1)) * 16 + f], hs[(pk.z >> GSH) * 16 + f]);
        if (base + 3 < cnt) atomicAdd(&agg[(pk.w & (G-1)) * 16 + f], hs[(pk.w >> GSH) * 16 + f]);
    }
    __syncthreads();
    const int n0 = k << GSH;
    for (int l = slot; l < G; l += 16) {
        int n = n0 + l;
        if (n < N) {
            float iq = isq[n];
            float a = (agg[l * 16 + f] + hs[n * 16 + f]) * iq;  // + self loop
            float p = fmaxf(a + bf, 0.f) * wf;
            p += __shfl_xor(p, 1, 16);
            p += __shfl_xor(p, 2, 16);
            p += __shfl_xor(p, 4, 16);
            p += __shfl_xor(p, 8, 16);
            if (f == 0) ts[n] = p * iq;
        }
    }
}

// Layer-2 scalar aggregation + epilogue.
__global__ __launch_bounds__(256) void k_agg2(
    const int* __restrict__ pairs, const int* __restrict__ boff,
    const int* __restrict__ bcnt, const float* __restrict__ ts,
    const float* __restrict__ isq, const float* __restrict__ b2,
    float* __restrict__ out, int N)
{
    __shared__ float a2[G];
    const int t = threadIdx.x, k = blockIdx.x;
    if (t < G) a2[t] = 0.f;
    const int beg = boff[k], cnt = bcnt[k];
    __syncthreads();
    for (int i = t; i < cnt; i += 256) {
        int p = pairs[beg + i];
        atomicAdd(&a2[p & (G - 1)], ts[p >> GSH]);
    }
    __syncthreads();
    if (t < G) {
        int n = (k << GSH) + t;
        if (n < N) out[n] = (a2[t] + ts[n]) * isq[n] + b2[0];
    }
}

extern "C" void kernel_launch(void* const* d_in, const int* in_sizes, int n_in,
                              void* d_out, int out_size, void* d_ws, size_t ws_size,
                              hipStream_t stream) {
    const float* x  = (const float*)d_in[0];
    const int*   ei = (const int*)d_in[1];
    const float* W1 = (const float*)d_in[2];
    const float* b1 = (const float*)d_in[3];
    const float* W2 = (const float*)d_in[4];
    const float* b2 = (const float*)d_in[5];
    const int N = in_sizes[0] / 256;
    const int E = in_sizes[1] / 2;
    const int* src = ei;
    const int* dst = ei + E;
    const int B = (N + G - 1) / G;           // 782

    char* w = (char*)d_ws;
    int*   deg    = (int*)w;   w += (size_t)N * 4;
    float* isq    = (float*)w; w += (size_t)N * 4;
    int*   bcnt   = (int*)w;   w += BMAX * 4;
    int*   boff   = (int*)w;   w += BMAX * 4;
    int*   cursor = (int*)w;   w += BMAX * 4;
    int*   pairs  = (int*)w;   w += ((size_t)E + 16 * BMAX) * 4;
    float* hs     = (float*)w; w += (size_t)N * 64;
    float* ts     = (float*)w; w += (size_t)N * 4;
    float* out    = (float*)d_out;

    hipMemsetAsync(deg, 0, (size_t)N * 4, stream);
    hipMemsetAsync(cursor, 0, BMAX * 4, stream);

    const int nbE = (E + 255) / 256;
    k_deg<<<nbE, 256, 0, stream>>>(dst, E, deg);
    k_isq<<<(N + 255) / 256, 256, 0, stream>>>(deg, isq, N);
    k_bcnt<<<B, G, 0, stream>>>(deg, N, bcnt);
    k_scanB<<<1, BMAX, 0, stream>>>(bcnt, B, boff);
    k_bin<<<nbE, 256, 0, stream>>>(src, dst, boff, cursor, pairs, E);

    const int ntiles = (N + 31) / 32;
    k_lin1<<<1024, 128, 0, stream>>>(x, W1, isq, hs, N, ntiles);

    k_agg1<<<B, 256, 0, stream>>>(pairs, boff, bcnt, hs, isq, b1, W2, ts, N);
    k_agg2<<<B, 256, 0, stream>>>(pairs, boff, bcnt, ts, isq, b2, out, N);
}

// Round 4
// 644.375 us; speedup vs baseline: 2.2811x; 2.2811x over previous
//
#include <hip/hip_runtime.h>

// GCN 2-layer: 256 -> 16 -> 1, N=100000, E=3.2M + self loops.
// R4: block-local-histogram counting scatter into fixed-capacity dst-buckets
// (G=128 nodes/bucket, capacity C), then LDS-tile aggregation per bucket.
//   out[d] = isq[d]*(sum_src ts[src] + ts[d]) + b2,  ts = (h2 @ W2)*isq
//   h2 = relu(isq[d]*(sum_src hs[src] + hs[d]) + b1), hs = (x @ W1)*isq
// Edge pack: (src<<7)|(dst&127). Per-node deg recomputed per bucket from bins.

#define G 128
#define GSH 7
#define CAP 6144            // bucket capacity; mean fill 4096, sigma 64 -> 32 sigma
#define BINTHREADS 1024
#define ITEMS 32            // edges per thread in k_bin2 (32768 per block)

__global__ void k_init(int* __restrict__ gcur, int B) {
    int i = threadIdx.x;
    if (i < B) gcur[i] = i * CAP;
}

// Counting scatter: per-block LDS histogram -> one bulk global claim per
// bucket -> contiguous ~168B runs per (block,bucket). No per-edge global atomics.
__global__ __launch_bounds__(BINTHREADS) void k_bin2(
    const int* __restrict__ src, const int* __restrict__ dst,
    int* __restrict__ gcur, int* __restrict__ pairs, int E, int B)
{
    __shared__ int hist[800];
    const int t = threadIdx.x;
    const int base4 = blockIdx.x * (BINTHREADS * ITEMS / 4);
    for (int i = t; i < 800; i += BINTHREADS) hist[i] = 0;
    __syncthreads();

    int4 dd[ITEMS / 4];
    #pragma unroll
    for (int r = 0; r < ITEMS / 4; ++r) {
        const int i4 = base4 + r * BINTHREADS + t;
        const int i = i4 << 2;
        int4 v;
        if (i + 3 < E) v = ((const int4*)dst)[i4];
        else {
            v.x = (i     < E) ? dst[i]     : -1;
            v.y = (i + 1 < E) ? dst[i + 1] : -1;
            v.z = (i + 2 < E) ? dst[i + 2] : -1;
            v.w = (i + 3 < E) ? dst[i + 3] : -1;
        }
        dd[r] = v;
        if (v.x >= 0) atomicAdd(&hist[v.x >> GSH], 1);
        if (v.y >= 0) atomicAdd(&hist[v.y >> GSH], 1);
        if (v.z >= 0) atomicAdd(&hist[v.z >> GSH], 1);
        if (v.w >= 0) atomicAdd(&hist[v.w >> GSH], 1);
    }
    __syncthreads();
    for (int i = t; i < B; i += BINTHREADS) {
        int c = hist[i];
        hist[i] = c ? atomicAdd(&gcur[i], c) : 0;   // bulk claim -> absolute base
    }
    __syncthreads();
    #pragma unroll
    for (int r = 0; r < ITEMS / 4; ++r) {
        const int i4 = base4 + r * BINTHREADS + t;
        const int i = i4 << 2;
        int4 s;
        if (i + 3 < E) s = ((const int4*)src)[i4];
        else {
            s.x = (i     < E) ? src[i]     : 0;
            s.y = (i + 1 < E) ? src[i + 1] : 0;
            s.z = (i + 2 < E) ? src[i + 2] : 0;
            s.w = (i + 3 < E) ? src[i + 3] : 0;
        }
        int4 v = dd[r];
        if (v.x >= 0) { int p = atomicAdd(&hist[v.x >> GSH], 1); pairs[p] = (s.x << GSH) | (v.x & (G - 1)); }
        if (v.y >= 0) { int p = atomicAdd(&hist[v.y >> GSH], 1); pairs[p] = (s.y << GSH) | (v.y & (G - 1)); }
        if (v.z >= 0) { int p = atomicAdd(&hist[v.z >> GSH], 1); pairs[p] = (s.z << GSH) | (v.z & (G - 1)); }
        if (v.w >= 0) { int p = atomicAdd(&hist[v.w >> GSH], 1); pairs[p] = (s.w << GSH) | (v.w & (G - 1)); }
    }
}

// Per-bucket degree histogram -> isq (replaces global k_deg + k_isq).
__global__ __launch_bounds__(256) void k_degb(
    const int* __restrict__ pairs, const int* __restrict__ gcur,
    float* __restrict__ isq, int N)
{
    __shared__ int h[G];
    const int t = threadIdx.x, k = blockIdx.x;
    if (t < G) h[t] = 0;
    const int beg = k * CAP;
    const int cnt = gcur[k] - beg;
    __syncthreads();
    for (int i = t; i < cnt; i += 256) atomicAdd(&h[pairs[beg + i] & (G - 1)], 1);
    __syncthreads();
    if (t < G) {
        int n = (k << GSH) + t;
        if (n < N) isq[n] = rsqrtf((float)(h[t] + 1));   // +1 self loop
    }
}

// hs[n][f] = dot(x[n,:], W1[:,f]) * isq[n].  2 nodes x 2 features / thread.
__global__ __launch_bounds__(128) void k_lin1(
    const float* __restrict__ x, const float* __restrict__ W1,
    const float* __restrict__ isq, float* __restrict__ hs, int N, int ntiles)
{
    __shared__ float xs[32][260];
    __shared__ float wT[16][260];
    const int t = threadIdx.x;
    #pragma unroll
    for (int i = 0; i < 32; ++i) {
        int idx = t + i * 128;               // 4096 elems of W1[256][16]
        wT[idx & 15][idx >> 4] = W1[idx];
    }
    const int np = t >> 3, fp = t & 7;
    for (int tile = blockIdx.x; tile < ntiles; tile += gridDim.x) {
        const int n0 = tile << 5;
        __syncthreads();
        #pragma unroll
        for (int i = 0; i < 16; ++i) {
            int fi = t + i * 128;
            int r = fi >> 6, c4 = fi & 63;
            int n = n0 + r;
            float4 v = (n < N) ? ((const float4*)(x + ((size_t)n << 8)))[c4]
                               : make_float4(0.f, 0.f, 0.f, 0.f);
            *(float4*)&xs[r][c4 * 4] = v;
        }
        __syncthreads();
        const float4* xr0 = (const float4*)&xs[2 * np][0];
        const float4* xr1 = (const float4*)&xs[2 * np + 1][0];
        const float4* wr0 = (const float4*)&wT[2 * fp][0];
        const float4* wr1 = (const float4*)&wT[2 * fp + 1][0];
        float a00 = 0.f, a01 = 0.f, a10 = 0.f, a11 = 0.f;
        #pragma unroll 8
        for (int k4 = 0; k4 < 64; ++k4) {
            float4 xa = xr0[k4], xb = xr1[k4];
            float4 wa = wr0[k4], wb = wr1[k4];
            a00 += xa.x * wa.x + xa.y * wa.y + xa.z * wa.z + xa.w * wa.w;
            a01 += xa.x * wb.x + xa.y * wb.y + xa.z * wb.z + xa.w * wb.w;
            a10 += xb.x * wa.x + xb.y * wa.y + xb.z * wa.z + xb.w * wa.w;
            a11 += xb.x * wb.x + xb.y * wb.y + xb.z * wb.z + xb.w * wb.w;
        }
        int na = n0 + 2 * np, nb = na + 1;
        int f0 = 2 * fp, f1 = f0 + 1;
        if (na < N) {
            float iq = isq[na];
            hs[na * 16 + f0] = a00 * iq;
            hs[na * 16 + f1] = a01 * iq;
        }
        if (nb < N) {
            float iq = isq[nb];
            hs[nb * 16 + f0] = a10 * iq;
            hs[nb * 16 + f1] = a11 * iq;
        }
    }
}

// Layer-1 aggregation into LDS tile + fused relu/W2/isq epilogue -> ts.
__global__ __launch_bounds__(256) void k_agg1(
    const int* __restrict__ pairs, const int* __restrict__ gcur,
    const float* __restrict__ hs, const float* __restrict__ isq,
    const float* __restrict__ b1, const float* __restrict__ W2,
    float* __restrict__ ts, int N)
{
    __shared__ float agg[G * 16];            // 8KB
    const int t = threadIdx.x, k = blockIdx.x;
    const int slot = t >> 4, f = t & 15;
    const float bf = b1[f], wf = W2[f];
    #pragma unroll
    for (int i = t; i < G * 16; i += 256) agg[i] = 0.f;
    const int beg = k * CAP;
    const int cnt = gcur[k] - beg;
    __syncthreads();
    const int4* p4 = (const int4*)(pairs + beg);   // CAP % 4 == 0
    const int nq = (cnt + 3) >> 2;
    for (int q = slot; q < nq; q += 16) {
        int4 pk = p4[q];
        int base = q << 2;
        if (base     < cnt) atomicAdd(&agg[(pk.x & (G-1)) * 16 + f], hs[(pk.x >> GSH) * 16 + f]);
        if (base + 1 < cnt) atomicAdd(&agg[(pk.y & (G-1)) * 16 + f], hs[(pk.y >> GSH) * 16 + f]);
        if (base + 2 < cnt) atomicAdd(&agg[(pk.z & (G-1)) * 16 + f], hs[(pk.z >> GSH) * 16 + f]);
        if (base + 3 < cnt) atomicAdd(&agg[(pk.w & (G-1)) * 16 + f], hs[(pk.w >> GSH) * 16 + f]);
    }
    __syncthreads();
    const int n0 = k << GSH;
    for (int l = slot; l < G; l += 16) {
        int n = n0 + l;
        if (n < N) {
            float iq = isq[n];
            float a = (agg[l * 16 + f] + hs[n * 16 + f]) * iq;  // + self loop
            float p = fmaxf(a + bf, 0.f) * wf;
            p += __shfl_xor(p, 1, 16);
            p += __shfl_xor(p, 2, 16);
            p += __shfl_xor(p, 4, 16);
            p += __shfl_xor(p, 8, 16);
            if (f == 0) ts[n] = p * iq;
        }
    }
}

// Layer-2 scalar aggregation + epilogue.
__global__ __launch_bounds__(256) void k_agg2(
    const int* __restrict__ pairs, const int* __restrict__ gcur,
    const float* __restrict__ ts, const float* __restrict__ isq,
    const float* __restrict__ b2, float* __restrict__ out, int N)
{
    __shared__ float a2[G];
    const int t = threadIdx.x, k = blockIdx.x;
    if (t < G) a2[t] = 0.f;
    const int beg = k * CAP;
    const int cnt = gcur[k] - beg;
    __syncthreads();
    for (int i = t; i < cnt; i += 256) {
        int p = pairs[beg + i];
        atomicAdd(&a2[p & (G - 1)], ts[p >> GSH]);
    }
    __syncthreads();
    if (t < G) {
        int n = (k << GSH) + t;
        if (n < N) out[n] = (a2[t] + ts[n]) * isq[n] + b2[0];
    }
}

extern "C" void kernel_launch(void* const* d_in, const int* in_sizes, int n_in,
                              void* d_out, int out_size, void* d_ws, size_t ws_size,
                              hipStream_t stream) {
    const float* x  = (const float*)d_in[0];
    const int*   ei = (const int*)d_in[1];
    const float* W1 = (const float*)d_in[2];
    const float* b1 = (const float*)d_in[3];
    const float* W2 = (const float*)d_in[4];
    const float* b2 = (const float*)d_in[5];
    const int N = in_sizes[0] / 256;
    const int E = in_sizes[1] / 2;
    const int* src = ei;
    const int* dst = ei + E;
    const int B = (N + G - 1) / G;           // 782

    char* w = (char*)d_ws;
    float* isq   = (float*)w; w += (size_t)N * 4;
    int*   gcur  = (int*)w;   w += 1024 * 4;
    int*   pairs = (int*)w;   w += (size_t)B * CAP * 4;   // 19.2 MB
    float* hs    = (float*)w; w += (size_t)N * 64;        // 6.4 MB
    float* ts    = (float*)w; w += (size_t)N * 4;
    float* out   = (float*)d_out;

    k_init<<<1, 1024, 0, stream>>>(gcur, B);

    const int nbBin = (E + BINTHREADS * ITEMS - 1) / (BINTHREADS * ITEMS);  // 98
    k_bin2<<<nbBin, BINTHREADS, 0, stream>>>(src, dst, gcur, pairs, E, B);

    k_degb<<<B, 256, 0, stream>>>(pairs, gcur, isq, N);

    const int ntiles = (N + 31) / 32;
    k_lin1<<<1024, 128, 0, stream>>>(x, W1, isq, hs, N, ntiles);

    k_agg1<<<B, 256, 0, stream>>>(pairs, gcur, hs, isq, b1, W2, ts, N);
    k_agg2<<<B, 256, 0, stream>>>(pairs, gcur, ts, isq, b2, out, N);
}

// Round 5
// 607.826 us; speedup vs baseline: 2.4183x; 1.0601x over previous
//
#include <hip/hip_runtime.h>
#include <hip/hip_fp16.h>

// GCN 2-layer: 256 -> 16 -> 1, N=100000, E=3.2M + self loops.
// R5: fp16 hs (3.2MB -> L2-resident, halves gather bytes) + G=64 buckets
// (B=1563 blocks -> ~24 waves/CU latency hiding in aggregation).
//   out[d] = isq[d]*(sum_src ts[src] + ts[d]) + b2,  ts = (h2 @ W2)*isq
//   h2 = relu(isq[d]*(sum_src hs[src] + hs[d]) + b1), hs = (x @ W1)*isq
// Edge pack: (src<<6)|(dst&63); bucket = dst>>6.

#define G 64
#define GSH 6
#define CAP 3072            // bucket capacity; mean fill 2048, sigma ~45 -> 22 sigma
#define HSIZE 1600          // >= B
#define BINTHREADS 1024
#define ITEMS 32            // edges per thread in k_bin2 (32768 per block)

__global__ void k_init(int* __restrict__ gcur, int B) {
    int i = blockIdx.x * blockDim.x + threadIdx.x;
    if (i < B) gcur[i] = i * CAP;
}

// Counting scatter: per-block LDS histogram -> one bulk global claim per
// bucket -> contiguous runs per (block,bucket). No per-edge global atomics.
__global__ __launch_bounds__(BINTHREADS) void k_bin2(
    const int* __restrict__ src, const int* __restrict__ dst,
    int* __restrict__ gcur, int* __restrict__ pairs, int E, int B)
{
    __shared__ int hist[HSIZE];
    const int t = threadIdx.x;
    const int base4 = blockIdx.x * (BINTHREADS * ITEMS / 4);
    for (int i = t; i < HSIZE; i += BINTHREADS) hist[i] = 0;
    __syncthreads();

    int4 dd[ITEMS / 4];
    #pragma unroll
    for (int r = 0; r < ITEMS / 4; ++r) {
        const int i4 = base4 + r * BINTHREADS + t;
        const int i = i4 << 2;
        int4 v;
        if (i + 3 < E) v = ((const int4*)dst)[i4];
        else {
            v.x = (i     < E) ? dst[i]     : -1;
            v.y = (i + 1 < E) ? dst[i + 1] : -1;
            v.z = (i + 2 < E) ? dst[i + 2] : -1;
            v.w = (i + 3 < E) ? dst[i + 3] : -1;
        }
        dd[r] = v;
        if (v.x >= 0) atomicAdd(&hist[v.x >> GSH], 1);
        if (v.y >= 0) atomicAdd(&hist[v.y >> GSH], 1);
        if (v.z >= 0) atomicAdd(&hist[v.z >> GSH], 1);
        if (v.w >= 0) atomicAdd(&hist[v.w >> GSH], 1);
    }
    __syncthreads();
    for (int i = t; i < B; i += BINTHREADS) {
        int c = hist[i];
        hist[i] = c ? atomicAdd(&gcur[i], c) : 0;   // bulk claim -> absolute base
    }
    __syncthreads();
    #pragma unroll
    for (int r = 0; r < ITEMS / 4; ++r) {
        const int i4 = base4 + r * BINTHREADS + t;
        const int i = i4 << 2;
        int4 s;
        if (i + 3 < E) s = ((const int4*)src)[i4];
        else {
            s.x = (i     < E) ? src[i]     : 0;
            s.y = (i + 1 < E) ? src[i + 1] : 0;
            s.z = (i + 2 < E) ? src[i + 2] : 0;
            s.w = (i + 3 < E) ? src[i + 3] : 0;
        }
        int4 v = dd[r];
        if (v.x >= 0) { int p = atomicAdd(&hist[v.x >> GSH], 1); pairs[p] = (s.x << GSH) | (v.x & (G - 1)); }
        if (v.y >= 0) { int p = atomicAdd(&hist[v.y >> GSH], 1); pairs[p] = (s.y << GSH) | (v.y & (G - 1)); }
        if (v.z >= 0) { int p = atomicAdd(&hist[v.z >> GSH], 1); pairs[p] = (s.z << GSH) | (v.z & (G - 1)); }
        if (v.w >= 0) { int p = atomicAdd(&hist[v.w >> GSH], 1); pairs[p] = (s.w << GSH) | (v.w & (G - 1)); }
    }
}

// Per-bucket degree histogram -> isq.
__global__ __launch_bounds__(256) void k_degb(
    const int* __restrict__ pairs, const int* __restrict__ gcur,
    float* __restrict__ isq, int N)
{
    __shared__ int h[G];
    const int t = threadIdx.x, k = blockIdx.x;
    if (t < G) h[t] = 0;
    const int beg = k * CAP;
    const int cnt = gcur[k] - beg;
    __syncthreads();
    for (int i = t; i < cnt; i += 256) atomicAdd(&h[pairs[beg + i] & (G - 1)], 1);
    __syncthreads();
    if (t < G) {
        int n = (k << GSH) + t;
        if (n < N) isq[n] = rsqrtf((float)(h[t] + 1));   // +1 self loop
    }
}

// hs16[n][f] = half( dot(x[n,:], W1[:,f]) * isq[n] ).  2 nodes x 2 feats / thread.
__global__ __launch_bounds__(128) void k_lin1(
    const float* __restrict__ x, const float* __restrict__ W1,
    const float* __restrict__ isq, __half* __restrict__ hs16, int N, int ntiles)
{
    __shared__ float xs[32][260];
    __shared__ float wT[16][260];
    const int t = threadIdx.x;
    #pragma unroll
    for (int i = 0; i < 32; ++i) {
        int idx = t + i * 128;               // 4096 elems of W1[256][16]
        wT[idx & 15][idx >> 4] = W1[idx];
    }
    const int np = t >> 3, fp = t & 7;
    for (int tile = blockIdx.x; tile < ntiles; tile += gridDim.x) {
        const int n0 = tile << 5;
        __syncthreads();
        #pragma unroll
        for (int i = 0; i < 16; ++i) {
            int fi = t + i * 128;
            int r = fi >> 6, c4 = fi & 63;
            int n = n0 + r;
            float4 v = (n < N) ? ((const float4*)(x + ((size_t)n << 8)))[c4]
                               : make_float4(0.f, 0.f, 0.f, 0.f);
            *(float4*)&xs[r][c4 * 4] = v;
        }
        __syncthreads();
        const float4* xr0 = (const float4*)&xs[2 * np][0];
        const float4* xr1 = (const float4*)&xs[2 * np + 1][0];
        const float4* wr0 = (const float4*)&wT[2 * fp][0];
        const float4* wr1 = (const float4*)&wT[2 * fp + 1][0];
        float a00 = 0.f, a01 = 0.f, a10 = 0.f, a11 = 0.f;
        #pragma unroll 8
        for (int k4 = 0; k4 < 64; ++k4) {
            float4 xa = xr0[k4], xb = xr1[k4];
            float4 wa = wr0[k4], wb = wr1[k4];
            a00 += xa.x * wa.x + xa.y * wa.y + xa.z * wa.z + xa.w * wa.w;
            a01 += xa.x * wb.x + xa.y * wb.y + xa.z * wb.z + xa.w * wb.w;
            a10 += xb.x * wa.x + xb.y * wa.y + xb.z * wa.z + xb.w * wa.w;
            a11 += xb.x * wb.x + xb.y * wb.y + xb.z * wb.z + xb.w * wb.w;
        }
        int na = n0 + 2 * np, nb = na + 1;
        int f0 = 2 * fp;
        if (na < N) {
            float iq = isq[na];
            *(__half2*)&hs16[na * 16 + f0] = __floats2half2_rn(a00 * iq, a01 * iq);
        }
        if (nb < N) {
            float iq = isq[nb];
            *(__half2*)&hs16[nb * 16 + f0] = __floats2half2_rn(a10 * iq, a11 * iq);
        }
    }
}

// Layer-1 aggregation into LDS tile + fused relu/W2/isq epilogue -> ts.
// 16 lanes (features) per edge; hs16 row = 32B coalesced L2-hit gather.
__global__ __launch_bounds__(256) void k_agg1(
    const int* __restrict__ pairs, const int* __restrict__ gcur,
    const __half* __restrict__ hs16, const float* __restrict__ isq,
    const float* __restrict__ b1, const float* __restrict__ W2,
    float* __restrict__ ts, int N)
{
    __shared__ float agg[G * 16];            // 4KB
    const int t = threadIdx.x, k = blockIdx.x;
    const int slot = t >> 4, f = t & 15;
    const float bf = b1[f], wf = W2[f];
    #pragma unroll
    for (int i = t; i < G * 16; i += 256) agg[i] = 0.f;
    const int beg = k * CAP;
    const int cnt = gcur[k] - beg;
    __syncthreads();
    const int4* p4 = (const int4*)(pairs + beg);   // CAP % 4 == 0
    const int nq = (cnt + 3) >> 2;
    for (int q = slot; q < nq; q += 16) {
        int4 pk = p4[q];
        int base = q << 2;
        if (base     < cnt) atomicAdd(&agg[(pk.x & (G-1)) * 16 + f], __half2float(hs16[(pk.x >> GSH) * 16 + f]));
        if (base + 1 < cnt) atomicAdd(&agg[(pk.y & (G-1)) * 16 + f], __half2float(hs16[(pk.y >> GSH) * 16 + f]));
        if (base + 2 < cnt) atomicAdd(&agg[(pk.z & (G-1)) * 16 + f], __half2float(hs16[(pk.z >> GSH) * 16 + f]));
        if (base + 3 < cnt) atomicAdd(&agg[(pk.w & (G-1)) * 16 + f], __half2float(hs16[(pk.w >> GSH) * 16 + f]));
    }
    __syncthreads();
    const int n0 = k << GSH;
    for (int l = slot; l < G; l += 16) {
        int n = n0 + l;
        if (n < N) {
            float iq = isq[n];
            float a = (agg[l * 16 + f] + __half2float(hs16[n * 16 + f])) * iq;  // + self
            float p = fmaxf(a + bf, 0.f) * wf;
            p += __shfl_xor(p, 1, 16);
            p += __shfl_xor(p, 2, 16);
            p += __shfl_xor(p, 4, 16);
            p += __shfl_xor(p, 8, 16);
            if (f == 0) ts[n] = p * iq;
        }
    }
}

// Layer-2 scalar aggregation + epilogue. ts table = 400KB, L2-resident.
__global__ __launch_bounds__(256) void k_agg2(
    const int* __restrict__ pairs, const int* __restrict__ gcur,
    const float* __restrict__ ts, const float* __restrict__ isq,
    const float* __restrict__ b2, float* __restrict__ out, int N)
{
    __shared__ float a2[G];
    const int t = threadIdx.x, k = blockIdx.x;
    if (t < G) a2[t] = 0.f;
    const int beg = k * CAP;
    const int cnt = gcur[k] - beg;
    __syncthreads();
    for (int i = t; i < cnt; i += 256) {
        int p = pairs[beg + i];
        atomicAdd(&a2[p & (G - 1)], ts[p >> GSH]);
    }
    __syncthreads();
    if (t < G) {
        int n = (k << GSH) + t;
        if (n < N) out[n] = (a2[t] + ts[n]) * isq[n] + b2[0];
    }
}

extern "C" void kernel_launch(void* const* d_in, const int* in_sizes, int n_in,
                              void* d_out, int out_size, void* d_ws, size_t ws_size,
                              hipStream_t stream) {
    const float* x  = (const float*)d_in[0];
    const int*   ei = (const int*)d_in[1];
    const float* W1 = (const float*)d_in[2];
    const float* b1 = (const float*)d_in[3];
    const float* W2 = (const float*)d_in[4];
    const float* b2 = (const float*)d_in[5];
    const int N = in_sizes[0] / 256;
    const int E = in_sizes[1] / 2;
    const int* src = ei;
    const int* dst = ei + E;
    const int B = (N + G - 1) / G;           // 1563

    char* w = (char*)d_ws;
    float*  isq   = (float*)w;  w += (size_t)N * 4;
    int*    gcur  = (int*)w;    w += HSIZE * 4;
    int*    pairs = (int*)w;    w += (size_t)B * CAP * 4;   // 19.2 MB
    __half* hs16  = (__half*)w; w += (size_t)N * 32;        // 3.2 MB
    float*  ts    = (float*)w;  w += (size_t)N * 4;
    float*  out   = (float*)d_out;

    k_init<<<(B + 255) / 256, 256, 0, stream>>>(gcur, B);

    const int nbBin = (E + BINTHREADS * ITEMS - 1) / (BINTHREADS * ITEMS);  // 98
    k_bin2<<<nbBin, BINTHREADS, 0, stream>>>(src, dst, gcur, pairs, E, B);

    k_degb<<<B, 256, 0, stream>>>(pairs, gcur, isq, N);

    const int ntiles = (N + 31) / 32;
    k_lin1<<<1024, 128, 0, stream>>>(x, W1, isq, hs16, N, ntiles);

    k_agg1<<<B, 256, 0, stream>>>(pairs, gcur, hs16, isq, b1, W2, ts, N);
    k_agg2<<<B, 256, 0, stream>>>(pairs, gcur, ts, isq, b2, out, N);
}

// Round 6
// 361.487 us; speedup vs baseline: 4.0663x; 1.6815x over previous
//
#include <hip/hip_runtime.h>
#include <hip/hip_fp16.h>

// GCN 2-layer: 256 -> 16 -> 1, N=100000, E=3.2M + self loops.
// R6: per-bucket counting sort by dst-local -> contiguous per-node runs ->
// atomic-free register-accumulating gathers with 8B/lane loads.
//   out[d] = isq[d]*(sum_src ts[src] + ts[d]) + b2,  ts = (h2 @ W2)*isq
//   h2 = relu(isq[d]*(sum_src hs[src] + hs[d]) + b1), hs = (x @ W1)*isq

#define G 64
#define GSH 6
#define CAP 3072            // bucket capacity; mean fill 2048, sigma ~45
#define HSIZE 1600          // >= B
#define BINTHREADS 1024
#define ITEMS 32            // edges per thread in k_bin2

__global__ void k_init(int* __restrict__ gcur, int B) {
    int i = blockIdx.x * blockDim.x + threadIdx.x;
    if (i < B) gcur[i] = i * CAP;
}

// Counting scatter into fixed-capacity dst-buckets (per-block LDS histogram,
// one bulk global claim per bucket). Unchanged from R5.
__global__ __launch_bounds__(BINTHREADS) void k_bin2(
    const int* __restrict__ src, const int* __restrict__ dst,
    int* __restrict__ gcur, int* __restrict__ pairs, int E, int B)
{
    __shared__ int hist[HSIZE];
    const int t = threadIdx.x;
    const int base4 = blockIdx.x * (BINTHREADS * ITEMS / 4);
    for (int i = t; i < HSIZE; i += BINTHREADS) hist[i] = 0;
    __syncthreads();

    int4 dd[ITEMS / 4];
    #pragma unroll
    for (int r = 0; r < ITEMS / 4; ++r) {
        const int i4 = base4 + r * BINTHREADS + t;
        const int i = i4 << 2;
        int4 v;
        if (i + 3 < E) v = ((const int4*)dst)[i4];
        else {
            v.x = (i     < E) ? dst[i]     : -1;
            v.y = (i + 1 < E) ? dst[i + 1] : -1;
            v.z = (i + 2 < E) ? dst[i + 2] : -1;
            v.w = (i + 3 < E) ? dst[i + 3] : -1;
        }
        dd[r] = v;
        if (v.x >= 0) atomicAdd(&hist[v.x >> GSH], 1);
        if (v.y >= 0) atomicAdd(&hist[v.y >> GSH], 1);
        if (v.z >= 0) atomicAdd(&hist[v.z >> GSH], 1);
        if (v.w >= 0) atomicAdd(&hist[v.w >> GSH], 1);
    }
    __syncthreads();
    for (int i = t; i < B; i += BINTHREADS) {
        int c = hist[i];
        hist[i] = c ? atomicAdd(&gcur[i], c) : 0;
    }
    __syncthreads();
    #pragma unroll
    for (int r = 0; r < ITEMS / 4; ++r) {
        const int i4 = base4 + r * BINTHREADS + t;
        const int i = i4 << 2;
        int4 s;
        if (i + 3 < E) s = ((const int4*)src)[i4];
        else {
            s.x = (i     < E) ? src[i]     : 0;
            s.y = (i + 1 < E) ? src[i + 1] : 0;
            s.z = (i + 2 < E) ? src[i + 2] : 0;
            s.w = (i + 3 < E) ? src[i + 3] : 0;
        }
        int4 v = dd[r];
        if (v.x >= 0) { int p = atomicAdd(&hist[v.x >> GSH], 1); pairs[p] = (s.x << GSH) | (v.x & (G - 1)); }
        if (v.y >= 0) { int p = atomicAdd(&hist[v.y >> GSH], 1); pairs[p] = (s.y << GSH) | (v.y & (G - 1)); }
        if (v.z >= 0) { int p = atomicAdd(&hist[v.z >> GSH], 1); pairs[p] = (s.z << GSH) | (v.z & (G - 1)); }
        if (v.w >= 0) { int p = atomicAdd(&hist[v.w >> GSH], 1); pairs[p] = (s.w << GSH) | (v.w & (G - 1)); }
    }
}

// Per-bucket counting sort by dst-local (6-bit key), in place. Produces:
// pairs[bucket region] = src indices sorted by dst-local; rowpg[k*65+l] =
// exclusive run offsets (l=0..64); isq from per-node counts.
__global__ __launch_bounds__(256) void k_sort(
    int* __restrict__ pairs, const int* __restrict__ gcur,
    int* __restrict__ rowpg, float* __restrict__ isq, int N)
{
    __shared__ int e[CAP];               // 12KB staged edges
    __shared__ int hist[G];
    __shared__ int cur[G];
    const int t = threadIdx.x, k = blockIdx.x;
    const int beg = k * CAP;
    const int cnt = gcur[k] - beg;
    if (t < G) hist[t] = 0;
    __syncthreads();
    for (int i = t; i < cnt; i += 256) {
        int p = pairs[beg + i];
        e[i] = p;
        atomicAdd(&hist[p & (G - 1)], 1);
    }
    __syncthreads();
    if (t < 64) {                        // wave 0: exclusive scan over 64 counts
        int c = hist[t];
        int v = c;
        #pragma unroll
        for (int off = 1; off < 64; off <<= 1) {
            int u = __shfl_up(v, off, 64);
            if (t >= off) v += u;
        }
        cur[t] = v - c;                  // exclusive prefix
        rowpg[k * 65 + t] = v - c;
        if (t == 63) rowpg[k * 65 + 64] = v;   // total = cnt
        int n = (k << GSH) + t;
        if (n < N) isq[n] = rsqrtf((float)(c + 1));   // +1 self loop
    }
    __syncthreads();
    for (int i = t; i < cnt; i += 256) {
        int p = e[i];
        int pos = atomicAdd(&cur[p & (G - 1)], 1);
        pairs[beg + pos] = p >> GSH;     // sorted src
    }
}

// hs16[n][f] = half( dot(x[n,:], W1[:,f]) * isq[n] ). Unchanged from R5.
__global__ __launch_bounds__(128) void k_lin1(
    const float* __restrict__ x, const float* __restrict__ W1,
    const float* __restrict__ isq, __half* __restrict__ hs16, int N, int ntiles)
{
    __shared__ float xs[32][260];
    __shared__ float wT[16][260];
    const int t = threadIdx.x;
    #pragma unroll
    for (int i = 0; i < 32; ++i) {
        int idx = t + i * 128;
        wT[idx & 15][idx >> 4] = W1[idx];
    }
    const int np = t >> 3, fp = t & 7;
    for (int tile = blockIdx.x; tile < ntiles; tile += gridDim.x) {
        const int n0 = tile << 5;
        __syncthreads();
        #pragma unroll
        for (int i = 0; i < 16; ++i) {
            int fi = t + i * 128;
            int r = fi >> 6, c4 = fi & 63;
            int n = n0 + r;
            float4 v = (n < N) ? ((const float4*)(x + ((size_t)n << 8)))[c4]
                               : make_float4(0.f, 0.f, 0.f, 0.f);
            *(float4*)&xs[r][c4 * 4] = v;
        }
        __syncthreads();
        const float4* xr0 = (const float4*)&xs[2 * np][0];
        const float4* xr1 = (const float4*)&xs[2 * np + 1][0];
        const float4* wr0 = (const float4*)&wT[2 * fp][0];
        const float4* wr1 = (const float4*)&wT[2 * fp + 1][0];
        float a00 = 0.f, a01 = 0.f, a10 = 0.f, a11 = 0.f;
        #pragma unroll 8
        for (int k4 = 0; k4 < 64; ++k4) {
            float4 xa = xr0[k4], xb = xr1[k4];
            float4 wa = wr0[k4], wb = wr1[k4];
            a00 += xa.x * wa.x + xa.y * wa.y + xa.z * wa.z + xa.w * wa.w;
            a01 += xa.x * wb.x + xa.y * wb.y + xa.z * wb.z + xa.w * wb.w;
            a10 += xb.x * wa.x + xb.y * wa.y + xb.z * wa.z + xb.w * wa.w;
            a11 += xb.x * wb.x + xb.y * wb.y + xb.z * wb.z + xb.w * wb.w;
        }
        int na = n0 + 2 * np, nb = na + 1;
        int f0 = 2 * fp;
        if (na < N) {
            float iq = isq[na];
            *(__half2*)&hs16[na * 16 + f0] = __floats2half2_rn(a00 * iq, a01 * iq);
        }
        if (nb < N) {
            float iq = isq[nb];
            *(__half2*)&hs16[nb * 16 + f0] = __floats2half2_rn(a10 * iq, a11 * iq);
        }
    }
}

// Layer-1 aggregation: 4 lanes per node (4 features each, 8B loads), run-scan
// with register accumulation, fused relu/W2/isq epilogue. No atomics.
__global__ __launch_bounds__(256) void k_agg1(
    const int* __restrict__ sorted, const int* __restrict__ rowpg,
    const __half* __restrict__ hs16, const float* __restrict__ isq,
    const float* __restrict__ b1, const float* __restrict__ W2,
    float* __restrict__ ts, int N)
{
    const int t = threadIdx.x, k = blockIdx.x;
    const int l = t >> 2, q = t & 3;     // node-local, feature-quad
    const int n = (k << GSH) + l;
    if (n >= N) return;
    const float2* h2 = (const float2*)hs16;        // 4 float2 per node row
    const int rbeg = k * CAP + rowpg[k * 65 + l];
    const int rend = k * CAP + rowpg[k * 65 + l + 1];
    float a0 = 0.f, a1 = 0.f, a2 = 0.f, a3 = 0.f;
    int j = rbeg;
    for (; j + 2 <= rend; j += 2) {
        int s0 = sorted[j], s1 = sorted[j + 1];
        float2 ra = h2[s0 * 4 + q];
        float2 rb = h2[s1 * 4 + q];
        union { float f; __half2 h; } ca0, ca1, cb0, cb1;
        ca0.f = ra.x; ca1.f = ra.y; cb0.f = rb.x; cb1.f = rb.y;
        float2 fa0 = __half22float2(ca0.h), fa1 = __half22float2(ca1.h);
        float2 fb0 = __half22float2(cb0.h), fb1 = __half22float2(cb1.h);
        a0 += fa0.x + fb0.x; a1 += fa0.y + fb0.y;
        a2 += fa1.x + fb1.x; a3 += fa1.y + fb1.y;
    }
    if (j < rend) {
        int s0 = sorted[j];
        float2 ra = h2[s0 * 4 + q];
        union { float f; __half2 h; } ca0, ca1;
        ca0.f = ra.x; ca1.f = ra.y;
        float2 fa0 = __half22float2(ca0.h), fa1 = __half22float2(ca1.h);
        a0 += fa0.x; a1 += fa0.y; a2 += fa1.x; a3 += fa1.y;
    }
    // self loop
    {
        float2 rs = h2[(size_t)n * 4 + q];
        union { float f; __half2 h; } c0, c1;
        c0.f = rs.x; c1.f = rs.y;
        float2 f0 = __half22float2(c0.h), f1 = __half22float2(c1.h);
        a0 += f0.x; a1 += f0.y; a2 += f1.x; a3 += f1.y;
    }
    const float iq = isq[n];
    const int f0i = q * 4;
    float p = fmaxf(a0 * iq + b1[f0i + 0], 0.f) * W2[f0i + 0]
            + fmaxf(a1 * iq + b1[f0i + 1], 0.f) * W2[f0i + 1]
            + fmaxf(a2 * iq + b1[f0i + 2], 0.f) * W2[f0i + 2]
            + fmaxf(a3 * iq + b1[f0i + 3], 0.f) * W2[f0i + 3];
    p += __shfl_xor(p, 1, 4);
    p += __shfl_xor(p, 2, 4);
    if (q == 0) ts[n] = p * iq;
}

// Layer-2: 1 lane per node, run-scan over sorted srcs, scalar ts gather.
// 4 buckets per block.
__global__ __launch_bounds__(256) void k_agg2(
    const int* __restrict__ sorted, const int* __restrict__ rowpg,
    const float* __restrict__ ts, const float* __restrict__ isq,
    const float* __restrict__ b2, float* __restrict__ out, int N, int B)
{
    const int t = threadIdx.x;
    const int k = blockIdx.x * 4 + (t >> 6);
    if (k >= B) return;
    const int l = t & 63;
    const int n = (k << GSH) + l;
    if (n >= N) return;
    const int rbeg = k * CAP + rowpg[k * 65 + l];
    const int rend = k * CAP + rowpg[k * 65 + l + 1];
    float acc = ts[n];                   // self loop
    int j = rbeg;
    for (; j + 4 <= rend; j += 4) {
        int s0 = sorted[j], s1 = sorted[j + 1], s2 = sorted[j + 2], s3 = sorted[j + 3];
        acc += (ts[s0] + ts[s1]) + (ts[s2] + ts[s3]);
    }
    for (; j < rend; ++j) acc += ts[sorted[j]];
    out[n] = acc * isq[n] + b2[0];
}

extern "C" void kernel_launch(void* const* d_in, const int* in_sizes, int n_in,
                              void* d_out, int out_size, void* d_ws, size_t ws_size,
                              hipStream_t stream) {
    const float* x  = (const float*)d_in[0];
    const int*   ei = (const int*)d_in[1];
    const float* W1 = (const float*)d_in[2];
    const float* b1 = (const float*)d_in[3];
    const float* W2 = (const float*)d_in[4];
    const float* b2 = (const float*)d_in[5];
    const int N = in_sizes[0] / 256;
    const int E = in_sizes[1] / 2;
    const int* src = ei;
    const int* dst = ei + E;
    const int B = (N + G - 1) / G;       // 1563

    char* w = (char*)d_ws;
    float*  isq   = (float*)w;  w += (size_t)N * 4;
    int*    gcur  = (int*)w;    w += HSIZE * 4;
    int*    pairs = (int*)w;    w += (size_t)B * CAP * 4;   // 19.2 MB
    int*    rowpg = (int*)w;    w += (size_t)B * 65 * 4;    // 406 KB
    __half* hs16  = (__half*)w; w += (size_t)N * 32;        // 3.2 MB
    float*  ts    = (float*)w;  w += (size_t)N * 4;
    float*  out   = (float*)d_out;

    k_init<<<(B + 255) / 256, 256, 0, stream>>>(gcur, B);

    const int nbBin = (E + BINTHREADS * ITEMS - 1) / (BINTHREADS * ITEMS);  // 98
    k_bin2<<<nbBin, BINTHREADS, 0, stream>>>(src, dst, gcur, pairs, E, B);

    k_sort<<<B, 256, 0, stream>>>(pairs, gcur, rowpg, isq, N);

    const int ntiles = (N + 31) / 32;
    k_lin1<<<1024, 128, 0, stream>>>(x, W1, isq, hs16, N, ntiles);

    k_agg1<<<B, 256, 0, stream>>>(pairs, rowpg, hs16, isq, b1, W2, ts, N);
    k_agg2<<<(B + 3) / 4, 256, 0, stream>>>(pairs, rowpg, ts, isq, b2, out, N, B);
}

// Round 7
// 330.185 us; speedup vs baseline: 4.4518x; 1.0948x over previous
//
#include <hip/hip_runtime.h>
#include <hip/hip_fp16.h>

// GCN 2-layer: 256 -> 16 -> 1, N=100000, E=3.2M + self loops.
// R7: k_lin1 rewritten as streaming thread-per-(node, feature-quad) GEMM:
// no x LDS tile, no per-tile syncs, W1 broadcast from 16KB LDS, 24 waves/CU.
// Rest of pipeline unchanged from R6 (bin -> sort -> agg1 -> agg2).

#define G 64
#define GSH 6
#define CAP 3072            // bucket capacity; mean fill 2048, sigma ~45
#define HSIZE 1600          // >= B
#define BINTHREADS 1024
#define ITEMS 32            // edges per thread in k_bin2

__global__ void k_init(int* __restrict__ gcur, int B) {
    int i = blockIdx.x * blockDim.x + threadIdx.x;
    if (i < B) gcur[i] = i * CAP;
}

// Counting scatter into fixed-capacity dst-buckets (per-block LDS histogram,
// one bulk global claim per bucket).
__global__ __launch_bounds__(BINTHREADS) void k_bin2(
    const int* __restrict__ src, const int* __restrict__ dst,
    int* __restrict__ gcur, int* __restrict__ pairs, int E, int B)
{
    __shared__ int hist[HSIZE];
    const int t = threadIdx.x;
    const int base4 = blockIdx.x * (BINTHREADS * ITEMS / 4);
    for (int i = t; i < HSIZE; i += BINTHREADS) hist[i] = 0;
    __syncthreads();

    int4 dd[ITEMS / 4];
    #pragma unroll
    for (int r = 0; r < ITEMS / 4; ++r) {
        const int i4 = base4 + r * BINTHREADS + t;
        const int i = i4 << 2;
        int4 v;
        if (i + 3 < E) v = ((const int4*)dst)[i4];
        else {
            v.x = (i     < E) ? dst[i]     : -1;
            v.y = (i + 1 < E) ? dst[i + 1] : -1;
            v.z = (i + 2 < E) ? dst[i + 2] : -1;
            v.w = (i + 3 < E) ? dst[i + 3] : -1;
        }
        dd[r] = v;
        if (v.x >= 0) atomicAdd(&hist[v.x >> GSH], 1);
        if (v.y >= 0) atomicAdd(&hist[v.y >> GSH], 1);
        if (v.z >= 0) atomicAdd(&hist[v.z >> GSH], 1);
        if (v.w >= 0) atomicAdd(&hist[v.w >> GSH], 1);
    }
    __syncthreads();
    for (int i = t; i < B; i += BINTHREADS) {
        int c = hist[i];
        hist[i] = c ? atomicAdd(&gcur[i], c) : 0;
    }
    __syncthreads();
    #pragma unroll
    for (int r = 0; r < ITEMS / 4; ++r) {
        const int i4 = base4 + r * BINTHREADS + t;
        const int i = i4 << 2;
        int4 s;
        if (i + 3 < E) s = ((const int4*)src)[i4];
        else {
            s.x = (i     < E) ? src[i]     : 0;
            s.y = (i + 1 < E) ? src[i + 1] : 0;
            s.z = (i + 2 < E) ? src[i + 2] : 0;
            s.w = (i + 3 < E) ? src[i + 3] : 0;
        }
        int4 v = dd[r];
        if (v.x >= 0) { int p = atomicAdd(&hist[v.x >> GSH], 1); pairs[p] = (s.x << GSH) | (v.x & (G - 1)); }
        if (v.y >= 0) { int p = atomicAdd(&hist[v.y >> GSH], 1); pairs[p] = (s.y << GSH) | (v.y & (G - 1)); }
        if (v.z >= 0) { int p = atomicAdd(&hist[v.z >> GSH], 1); pairs[p] = (s.z << GSH) | (v.z & (G - 1)); }
        if (v.w >= 0) { int p = atomicAdd(&hist[v.w >> GSH], 1); pairs[p] = (s.w << GSH) | (v.w & (G - 1)); }
    }
}

// Per-bucket counting sort by dst-local (6-bit key), in place.
__global__ __launch_bounds__(256) void k_sort(
    int* __restrict__ pairs, const int* __restrict__ gcur,
    int* __restrict__ rowpg, float* __restrict__ isq, int N)
{
    __shared__ int e[CAP];
    __shared__ int hist[G];
    __shared__ int cur[G];
    const int t = threadIdx.x, k = blockIdx.x;
    const int beg = k * CAP;
    const int cnt = gcur[k] - beg;
    if (t < G) hist[t] = 0;
    __syncthreads();
    for (int i = t; i < cnt; i += 256) {
        int p = pairs[beg + i];
        e[i] = p;
        atomicAdd(&hist[p & (G - 1)], 1);
    }
    __syncthreads();
    if (t < 64) {
        int c = hist[t];
        int v = c;
        #pragma unroll
        for (int off = 1; off < 64; off <<= 1) {
            int u = __shfl_up(v, off, 64);
            if (t >= off) v += u;
        }
        cur[t] = v - c;
        rowpg[k * 65 + t] = v - c;
        if (t == 63) rowpg[k * 65 + 64] = v;
        int n = (k << GSH) + t;
        if (n < N) isq[n] = rsqrtf((float)(c + 1));   // +1 self loop
    }
    __syncthreads();
    for (int i = t; i < cnt; i += 256) {
        int p = e[i];
        int pos = atomicAdd(&cur[p & (G - 1)], 1);
        pairs[beg + pos] = p >> GSH;
    }
}

// hs16[n][f] = half( dot(x[n,:], W1[:,f]) * isq[n] ).
// Thread = (node, feature-quad q). Lane quads share the x row address
// (hardware-merged); W1 k-major in LDS, 4-address b128 multicast on
// disjoint banks. No per-tile syncs -> deep software pipelining.
__global__ __launch_bounds__(256) void k_lin1(
    const float* __restrict__ x, const float* __restrict__ W1,
    const float* __restrict__ isq, __half* __restrict__ hs16, int N)
{
    __shared__ float wL[256 * 16];       // wL[k*16+f], 16KB (W1 is k-major)
    {
        const float4* w4 = (const float4*)W1;
        float4* s4 = (float4*)wL;
        for (int i = threadIdx.x; i < 1024; i += 256) s4[i] = w4[i];
    }
    __syncthreads();
    const int gid = blockIdx.x * 256 + threadIdx.x;
    const int n = gid >> 2, q = gid & 3;
    if (n >= N) return;
    const float4* xr = (const float4*)(x + ((size_t)n << 8));
    const float4* wb = (const float4*)wL + q;     // wb[k*4] = W[k][q*4..q*4+3]
    float a0 = 0.f, a1 = 0.f, a2 = 0.f, a3 = 0.f;
    #pragma unroll 8
    for (int k4 = 0; k4 < 64; ++k4) {
        float4 xa = xr[k4];
        float4 w0 = wb[(k4 * 4 + 0) * 4];
        float4 w1 = wb[(k4 * 4 + 1) * 4];
        float4 w2 = wb[(k4 * 4 + 2) * 4];
        float4 w3 = wb[(k4 * 4 + 3) * 4];
        a0 += xa.x * w0.x + xa.y * w1.x + xa.z * w2.x + xa.w * w3.x;
        a1 += xa.x * w0.y + xa.y * w1.y + xa.z * w2.y + xa.w * w3.y;
        a2 += xa.x * w0.z + xa.y * w1.z + xa.z * w2.z + xa.w * w3.z;
        a3 += xa.x * w0.w + xa.y * w1.w + xa.z * w2.w + xa.w * w3.w;
    }
    const float iq = isq[n];
    __half2 h0 = __floats2half2_rn(a0 * iq, a1 * iq);
    __half2 h1 = __floats2half2_rn(a2 * iq, a3 * iq);
    __half2* o = (__half2*)&hs16[n * 16 + q * 4];
    o[0] = h0;
    o[1] = h1;
}

// Layer-1 aggregation: 4 lanes per node (4 features each, 8B loads), run-scan
// with register accumulation, fused relu/W2/isq epilogue. No atomics.
__global__ __launch_bounds__(256) void k_agg1(
    const int* __restrict__ sorted, const int* __restrict__ rowpg,
    const __half* __restrict__ hs16, const float* __restrict__ isq,
    const float* __restrict__ b1, const float* __restrict__ W2,
    float* __restrict__ ts, int N)
{
    const int t = threadIdx.x, k = blockIdx.x;
    const int l = t >> 2, q = t & 3;
    const int n = (k << GSH) + l;
    if (n >= N) return;
    const float2* h2 = (const float2*)hs16;
    const int rbeg = k * CAP + rowpg[k * 65 + l];
    const int rend = k * CAP + rowpg[k * 65 + l + 1];
    float a0 = 0.f, a1 = 0.f, a2 = 0.f, a3 = 0.f;
    int j = rbeg;
    for (; j + 2 <= rend; j += 2) {
        int s0 = sorted[j], s1 = sorted[j + 1];
        float2 ra = h2[s0 * 4 + q];
        float2 rb = h2[s1 * 4 + q];
        union { float f; __half2 h; } ca0, ca1, cb0, cb1;
        ca0.f = ra.x; ca1.f = ra.y; cb0.f = rb.x; cb1.f = rb.y;
        float2 fa0 = __half22float2(ca0.h), fa1 = __half22float2(ca1.h);
        float2 fb0 = __half22float2(cb0.h), fb1 = __half22float2(cb1.h);
        a0 += fa0.x + fb0.x; a1 += fa0.y + fb0.y;
        a2 += fa1.x + fb1.x; a3 += fa1.y + fb1.y;
    }
    if (j < rend) {
        int s0 = sorted[j];
        float2 ra = h2[s0 * 4 + q];
        union { float f; __half2 h; } ca0, ca1;
        ca0.f = ra.x; ca1.f = ra.y;
        float2 fa0 = __half22float2(ca0.h), fa1 = __half22float2(ca1.h);
        a0 += fa0.x; a1 += fa0.y; a2 += fa1.x; a3 += fa1.y;
    }
    {
        float2 rs = h2[(size_t)n * 4 + q];
        union { float f; __half2 h; } c0, c1;
        c0.f = rs.x; c1.f = rs.y;
        float2 f0 = __half22float2(c0.h), f1 = __half22float2(c1.h);
        a0 += f0.x; a1 += f0.y; a2 += f1.x; a3 += f1.y;
    }
    const float iq = isq[n];
    const int f0i = q * 4;
    float p = fmaxf(a0 * iq + b1[f0i + 0], 0.f) * W2[f0i + 0]
            + fmaxf(a1 * iq + b1[f0i + 1], 0.f) * W2[f0i + 1]
            + fmaxf(a2 * iq + b1[f0i + 2], 0.f) * W2[f0i + 2]
            + fmaxf(a3 * iq + b1[f0i + 3], 0.f) * W2[f0i + 3];
    p += __shfl_xor(p, 1, 4);
    p += __shfl_xor(p, 2, 4);
    if (q == 0) ts[n] = p * iq;
}

// Layer-2: 1 lane per node, run-scan over sorted srcs, scalar ts gather.
__global__ __launch_bounds__(256) void k_agg2(
    const int* __restrict__ sorted, const int* __restrict__ rowpg,
    const float* __restrict__ ts, const float* __restrict__ isq,
    const float* __restrict__ b2, float* __restrict__ out, int N, int B)
{
    const int t = threadIdx.x;
    const int k = blockIdx.x * 4 + (t >> 6);
    if (k >= B) return;
    const int l = t & 63;
    const int n = (k << GSH) + l;
    if (n >= N) return;
    const int rbeg = k * CAP + rowpg[k * 65 + l];
    const int rend = k * CAP + rowpg[k * 65 + l + 1];
    float acc = ts[n];
    int j = rbeg;
    for (; j + 4 <= rend; j += 4) {
        int s0 = sorted[j], s1 = sorted[j + 1], s2 = sorted[j + 2], s3 = sorted[j + 3];
        acc += (ts[s0] + ts[s1]) + (ts[s2] + ts[s3]);
    }
    for (; j < rend; ++j) acc += ts[sorted[j]];
    out[n] = acc * isq[n] + b2[0];
}

extern "C" void kernel_launch(void* const* d_in, const int* in_sizes, int n_in,
                              void* d_out, int out_size, void* d_ws, size_t ws_size,
                              hipStream_t stream) {
    const float* x  = (const float*)d_in[0];
    const int*   ei = (const int*)d_in[1];
    const float* W1 = (const float*)d_in[2];
    const float* b1 = (const float*)d_in[3];
    const float* W2 = (const float*)d_in[4];
    const float* b2 = (const float*)d_in[5];
    const int N = in_sizes[0] / 256;
    const int E = in_sizes[1] / 2;
    const int* src = ei;
    const int* dst = ei + E;
    const int B = (N + G - 1) / G;       // 1563

    char* w = (char*)d_ws;
    float*  isq   = (float*)w;  w += (size_t)N * 4;
    int*    gcur  = (int*)w;    w += HSIZE * 4;
    int*    pairs = (int*)w;    w += (size_t)B * CAP * 4;   // 19.2 MB
    int*    rowpg = (int*)w;    w += (size_t)B * 65 * 4;    // 406 KB
    __half* hs16  = (__half*)w; w += (size_t)N * 32;        // 3.2 MB
    float*  ts    = (float*)w;  w += (size_t)N * 4;
    float*  out   = (float*)d_out;

    k_init<<<(B + 255) / 256, 256, 0, stream>>>(gcur, B);

    const int nbBin = (E + BINTHREADS * ITEMS - 1) / (BINTHREADS * ITEMS);  // 98
    k_bin2<<<nbBin, BINTHREADS, 0, stream>>>(src, dst, gcur, pairs, E, B);

    k_sort<<<B, 256, 0, stream>>>(pairs, gcur, rowpg, isq, N);

    k_lin1<<<(N * 4 + 255) / 256, 256, 0, stream>>>(x, W1, isq, hs16, N);

    k_agg1<<<B, 256, 0, stream>>>(pairs, rowpg, hs16, isq, b1, W2, ts, N);
    k_agg2<<<(B + 3) / 4, 256, 0, stream>>>(pairs, rowpg, ts, isq, b2, out, N, B);
}

// Round 8
// 315.403 us; speedup vs baseline: 4.6604x; 1.0469x over previous
//
#include <hip/hip_runtime.h>
#include <hip/hip_fp16.h>

// GCN 2-layer: 256 -> 16 -> 1, N=100000, E=3.2M + self loops.
// R8: two-level radix. k_p1 bins edges by super-bucket (256 nodes, dst>>8);
// k_sortsb counting-sorts each super-bucket entirely in LDS (8-bit local key),
// emitting fully dst-sorted src lists + rowp + isq in one pass.
//   out[d] = isq[d]*(sum_src ts[src] + ts[d]) + b2,  ts = (h2 @ W2)*isq
//   h2 = relu(isq[d]*(sum_src hs[src] + hs[d]) + b1), hs = (x @ W1)*isq
// Edge pack in pass1: (src<<8)|(dst&255), sb = dst>>8 (src<2^17 -> 25 bits).

#define SBSH 8              // 256 nodes per super-bucket
#define SBCAP 10240         // capacity (mean 8168, sigma ~90 -> +23 sigma)
#define HPAD 400            // >= Bsb = ceil(N/256) = 391
#define BINTHREADS 1024
#define ITEMS 32            // edges per thread in k_p1

__global__ void k_init(int* __restrict__ gcur, int Bsb) {
    int i = blockIdx.x * blockDim.x + threadIdx.x;
    if (i < Bsb) gcur[i] = i * SBCAP;
}

// Pass 1: counting scatter into super-bucket regions. Per-block LDS histogram,
// one bulk global claim per super-bucket, ~84-int runs (amp ~1.2).
__global__ __launch_bounds__(BINTHREADS) void k_p1(
    const int* __restrict__ src, const int* __restrict__ dst,
    int* __restrict__ gcur, int* __restrict__ pairs, int E, int Bsb)
{
    __shared__ int hist[HPAD];
    const int t = threadIdx.x;
    const int base4 = blockIdx.x * (BINTHREADS * ITEMS / 4);
    for (int i = t; i < HPAD; i += BINTHREADS) hist[i] = 0;
    __syncthreads();

    int4 dd[ITEMS / 4];
    #pragma unroll
    for (int r = 0; r < ITEMS / 4; ++r) {
        const int i4 = base4 + r * BINTHREADS + t;
        const int i = i4 << 2;
        int4 v;
        if (i + 3 < E) v = ((const int4*)dst)[i4];
        else {
            v.x = (i     < E) ? dst[i]     : -1;
            v.y = (i + 1 < E) ? dst[i + 1] : -1;
            v.z = (i + 2 < E) ? dst[i + 2] : -1;
            v.w = (i + 3 < E) ? dst[i + 3] : -1;
        }
        dd[r] = v;
        if (v.x >= 0) atomicAdd(&hist[v.x >> SBSH], 1);
        if (v.y >= 0) atomicAdd(&hist[v.y >> SBSH], 1);
        if (v.z >= 0) atomicAdd(&hist[v.z >> SBSH], 1);
        if (v.w >= 0) atomicAdd(&hist[v.w >> SBSH], 1);
    }
    __syncthreads();
    for (int i = t; i < Bsb; i += BINTHREADS) {
        int c = hist[i];
        hist[i] = c ? atomicAdd(&gcur[i], c) : 0;   // bulk claim -> abs base
    }
    __syncthreads();
    #pragma unroll
    for (int r = 0; r < ITEMS / 4; ++r) {
        const int i4 = base4 + r * BINTHREADS + t;
        const int i = i4 << 2;
        int4 s;
        if (i + 3 < E) s = ((const int4*)src)[i4];
        else {
            s.x = (i     < E) ? src[i]     : 0;
            s.y = (i + 1 < E) ? src[i + 1] : 0;
            s.z = (i + 2 < E) ? src[i + 2] : 0;
            s.w = (i + 3 < E) ? src[i + 3] : 0;
        }
        int4 v = dd[r];
        if (v.x >= 0) { int p = atomicAdd(&hist[v.x >> SBSH], 1); pairs[p] = (s.x << SBSH) | (v.x & 255); }
        if (v.y >= 0) { int p = atomicAdd(&hist[v.y >> SBSH], 1); pairs[p] = (s.y << SBSH) | (v.y & 255); }
        if (v.z >= 0) { int p = atomicAdd(&hist[v.z >> SBSH], 1); pairs[p] = (s.z << SBSH) | (v.z & 255); }
        if (v.w >= 0) { int p = atomicAdd(&hist[v.w >> SBSH], 1); pairs[p] = (s.w << SBSH) | (v.w & 255); }
    }
}

// Pass 2: per-super-bucket counting sort by 8-bit local dst, fully in LDS.
// Emits: pairs region <- src sorted by dst-local (coalesced write-back);
// rowp[sb*257 + l] = exclusive run offsets (257 entries); isq.
__global__ __launch_bounds__(1024) void k_sortsb(
    int* __restrict__ pairs, const int* __restrict__ gcur,
    int* __restrict__ rowp, float* __restrict__ isq, int N)
{
    __shared__ int e[SBCAP];             // 40KB staged edges
    __shared__ int hist[256];
    __shared__ int cur[256];
    __shared__ int wsum[4];
    const int t = threadIdx.x, sb = blockIdx.x;
    const int beg = sb * SBCAP;
    const int cnt = gcur[sb] - beg;
    if (t < 256) hist[t] = 0;
    __syncthreads();
    for (int i = t; i < cnt; i += 1024) {
        int p = pairs[beg + i];
        e[i] = p;
        atomicAdd(&hist[p & 255], 1);
    }
    __syncthreads();
    int c = 0, v = 0;
    if (t < 256) {                       // 4-wave scan of 256 counts
        const int lane = t & 63, w = t >> 6;
        c = hist[t];
        v = c;
        #pragma unroll
        for (int off = 1; off < 64; off <<= 1) {
            int u = __shfl_up(v, off, 64);
            if (lane >= off) v += u;
        }
        if (lane == 63) wsum[w] = v;
    }
    __syncthreads();
    if (t < 256) {
        const int w = t >> 6;
        int add = 0;
        #pragma unroll
        for (int i = 0; i < 3; ++i) if (i < w) add += wsum[i];
        int inc = v + add;               // inclusive prefix
        int exc = inc - c;
        cur[t] = exc;
        rowp[sb * 257 + t] = exc;
        if (t == 255) rowp[sb * 257 + 256] = inc;   // == cnt
        int n = (sb << SBSH) + t;
        if (n < N) isq[n] = rsqrtf((float)(c + 1)); // +1 self loop
    }
    __syncthreads();
    for (int i = t; i < cnt; i += 1024) {
        int p = e[i];
        int pos = atomicAdd(&cur[p & 255], 1);
        pairs[beg + pos] = p >> SBSH;    // sorted src
    }
}

// hs16[n][f] = half( dot(x[n,:], W1[:,f]) * isq[n] ). Streaming, no x tile.
__global__ __launch_bounds__(256) void k_lin1(
    const float* __restrict__ x, const float* __restrict__ W1,
    const float* __restrict__ isq, __half* __restrict__ hs16, int N)
{
    __shared__ float wL[256 * 16];       // k-major, 16KB
    {
        const float4* w4 = (const float4*)W1;
        float4* s4 = (float4*)wL;
        for (int i = threadIdx.x; i < 1024; i += 256) s4[i] = w4[i];
    }
    __syncthreads();
    const int gid = blockIdx.x * 256 + threadIdx.x;
    const int n = gid >> 2, q = gid & 3;
    if (n >= N) return;
    const float4* xr = (const float4*)(x + ((size_t)n << 8));
    const float4* wb = (const float4*)wL + q;
    float a0 = 0.f, a1 = 0.f, a2 = 0.f, a3 = 0.f;
    #pragma unroll 8
    for (int k4 = 0; k4 < 64; ++k4) {
        float4 xa = xr[k4];
        float4 w0 = wb[(k4 * 4 + 0) * 4];
        float4 w1 = wb[(k4 * 4 + 1) * 4];
        float4 w2 = wb[(k4 * 4 + 2) * 4];
        float4 w3 = wb[(k4 * 4 + 3) * 4];
        a0 += xa.x * w0.x + xa.y * w1.x + xa.z * w2.x + xa.w * w3.x;
        a1 += xa.x * w0.y + xa.y * w1.y + xa.z * w2.y + xa.w * w3.y;
        a2 += xa.x * w0.z + xa.y * w1.z + xa.z * w2.z + xa.w * w3.z;
        a3 += xa.x * w0.w + xa.y * w1.w + xa.z * w2.w + xa.w * w3.w;
    }
    const float iq = isq[n];
    __half2 h0 = __floats2half2_rn(a0 * iq, a1 * iq);
    __half2 h1 = __floats2half2_rn(a2 * iq, a3 * iq);
    __half2* o = (__half2*)&hs16[n * 16 + q * 4];
    o[0] = h0;
    o[1] = h1;
}

// Layer-1 aggregation: 4 lanes per node (4 features each, 8B loads), run-scan
// with register accumulation, fused relu/W2/isq epilogue. No atomics.
// Block = 64-node group g; sb = g>>2, local base = (g&3)*64.
__global__ __launch_bounds__(256) void k_agg1(
    const int* __restrict__ sorted, const int* __restrict__ rowp,
    const __half* __restrict__ hs16, const float* __restrict__ isq,
    const float* __restrict__ b1, const float* __restrict__ W2,
    float* __restrict__ ts, int N)
{
    const int t = threadIdx.x, g = blockIdx.x;
    const int l = t >> 2, q = t & 3;
    const int n = g * 64 + l;
    if (n >= N) return;
    const int sb = n >> SBSH, L = n & 255;
    const int rbeg = sb * SBCAP + rowp[sb * 257 + L];
    const int rend = sb * SBCAP + rowp[sb * 257 + L + 1];
    const float2* h2 = (const float2*)hs16;
    float a0 = 0.f, a1 = 0.f, a2 = 0.f, a3 = 0.f;
    int j = rbeg;
    for (; j + 2 <= rend; j += 2) {
        int s0 = sorted[j], s1 = sorted[j + 1];
        float2 ra = h2[s0 * 4 + q];
        float2 rb = h2[s1 * 4 + q];
        union { float f; __half2 h; } ca0, ca1, cb0, cb1;
        ca0.f = ra.x; ca1.f = ra.y; cb0.f = rb.x; cb1.f = rb.y;
        float2 fa0 = __half22float2(ca0.h), fa1 = __half22float2(ca1.h);
        float2 fb0 = __half22float2(cb0.h), fb1 = __half22float2(cb1.h);
        a0 += fa0.x + fb0.x; a1 += fa0.y + fb0.y;
        a2 += fa1.x + fb1.x; a3 += fa1.y + fb1.y;
    }
    if (j < rend) {
        int s0 = sorted[j];
        float2 ra = h2[s0 * 4 + q];
        union { float f; __half2 h; } ca0, ca1;
        ca0.f = ra.x; ca1.f = ra.y;
        float2 fa0 = __half22float2(ca0.h), fa1 = __half22float2(ca1.h);
        a0 += fa0.x; a1 += fa0.y; a2 += fa1.x; a3 += fa1.y;
    }
    {   // self loop
        float2 rs = h2[(size_t)n * 4 + q];
        union { float f; __half2 h; } c0, c1;
        c0.f = rs.x; c1.f = rs.y;
        float2 f0 = __half22float2(c0.h), f1 = __half22float2(c1.h);
        a0 += f0.x; a1 += f0.y; a2 += f1.x; a3 += f1.y;
    }
    const float iq = isq[n];
    const int f0i = q * 4;
    float p = fmaxf(a0 * iq + b1[f0i + 0], 0.f) * W2[f0i + 0]
            + fmaxf(a1 * iq + b1[f0i + 1], 0.f) * W2[f0i + 1]
            + fmaxf(a2 * iq + b1[f0i + 2], 0.f) * W2[f0i + 2]
            + fmaxf(a3 * iq + b1[f0i + 3], 0.f) * W2[f0i + 3];
    p += __shfl_xor(p, 1, 4);
    p += __shfl_xor(p, 2, 4);
    if (q == 0) ts[n] = p * iq;
}

// Layer-2: 1 thread per node, run-scan over sorted srcs, scalar ts gather.
__global__ __launch_bounds__(256) void k_agg2(
    const int* __restrict__ sorted, const int* __restrict__ rowp,
    const float* __restrict__ ts, const float* __restrict__ isq,
    const float* __restrict__ b2, float* __restrict__ out, int N)
{
    const int n = blockIdx.x * 256 + threadIdx.x;
    if (n >= N) return;
    const int sb = n >> SBSH, L = n & 255;
    const int rbeg = sb * SBCAP + rowp[sb * 257 + L];
    const int rend = sb * SBCAP + rowp[sb * 257 + L + 1];
    float acc = ts[n];                   // self loop
    int j = rbeg;
    for (; j + 4 <= rend; j += 4) {
        int s0 = sorted[j], s1 = sorted[j + 1], s2 = sorted[j + 2], s3 = sorted[j + 3];
        acc += (ts[s0] + ts[s1]) + (ts[s2] + ts[s3]);
    }
    for (; j < rend; ++j) acc += ts[sorted[j]];
    out[n] = acc * isq[n] + b2[0];
}

extern "C" void kernel_launch(void* const* d_in, const int* in_sizes, int n_in,
                              void* d_out, int out_size, void* d_ws, size_t ws_size,
                              hipStream_t stream) {
    const float* x  = (const float*)d_in[0];
    const int*   ei = (const int*)d_in[1];
    const float* W1 = (const float*)d_in[2];
    const float* b1 = (const float*)d_in[3];
    const float* W2 = (const float*)d_in[4];
    const float* b2 = (const float*)d_in[5];
    const int N = in_sizes[0] / 256;
    const int E = in_sizes[1] / 2;
    const int* src = ei;
    const int* dst = ei + E;
    const int Bsb = (N + 255) >> SBSH;   // 391

    char* w = (char*)d_ws;
    float*  isq   = (float*)w;  w += (size_t)N * 4;
    int*    gcur  = (int*)w;    w += HPAD * 4;
    int*    pairs = (int*)w;    w += (size_t)Bsb * SBCAP * 4;   // 16.0 MB
    int*    rowp  = (int*)w;    w += (size_t)Bsb * 257 * 4;     // 402 KB
    __half* hs16  = (__half*)w; w += (size_t)N * 32;            // 3.2 MB
    float*  ts    = (float*)w;  w += (size_t)N * 4;
    float*  out   = (float*)d_out;

    k_init<<<(Bsb + 255) / 256, 256, 0, stream>>>(gcur, Bsb);

    const int nbBin = (E + BINTHREADS * ITEMS - 1) / (BINTHREADS * ITEMS);  // 98
    k_p1<<<nbBin, BINTHREADS, 0, stream>>>(src, dst, gcur, pairs, E, Bsb);

    k_sortsb<<<Bsb, 1024, 0, stream>>>(pairs, gcur, rowp, isq, N);

    k_lin1<<<(N * 4 + 255) / 256, 256, 0, stream>>>(x, W1, isq, hs16, N);

    k_agg1<<<(N + 63) / 64, 256, 0, stream>>>(pairs, rowp, hs16, isq, b1, W2, ts, N);
    k_agg2<<<(N + 255) / 256, 256, 0, stream>>>(pairs, rowp, ts, isq, b2, out, N);
}